// Round 3
// baseline (23.808 us; speedup 1.0000x reference)
//
#include <hip/hip_runtime.h>

#define D 128
#define BATCH 16384
#define PITCH 132   // slab pitch in floats: 16B-aligned rows, spreads banks

typedef float f32x4 __attribute__((ext_vector_type(4)));
typedef short bh8 __attribute__((ext_vector_type(8)));

__device__ __forceinline__ unsigned short f2bf(float f) {
    unsigned u = __float_as_uint(f);
    u += 0x7FFFu + ((u >> 16) & 1u);   // round-to-nearest-even
    return (unsigned short)(u >> 16);
}

// Fused prep: block x in [0,128]:
//   x < 128: W2T[j][x] = bf16( sum_y (sum_z T[x,y,z] tv[z]) * op_w[j,y] )
//   x ==128: bias2[j]  =       sum_y (sum_z B[y,z]  tv[z]) * op_w[j,y] + op_b[j]
__global__ __launch_bounds__(256) void prep(
    const float* __restrict__ T, const float* __restrict__ Bm,
    const float* __restrict__ tv, const float* __restrict__ op_w,
    const float* __restrict__ op_b, unsigned short* __restrict__ W2T,
    float* __restrict__ bias2)
{
    __shared__ float slab[D * PITCH];
    __shared__ float m_s[D];
    const int x = blockIdx.x;
    const int t = threadIdx.x;
    const int l = t & 31;     // lane within 32-group
    const int rg = t >> 5;    // row group 0..7

    const float* src = (x < D) ? (T + (size_t)x * D * D) : Bm;
    // stage source slab (64 KB) coalesced
#pragma unroll
    for (int i = 0; i < 16; ++i) {
        const int e = i * 1024 + t * 4;
        const int y = e >> 7, z = e & 127;
        *(f32x4*)&slab[y * PITCH + z] = *(const f32x4*)(src + e);
    }
    const f32x4 tvv = *(const f32x4*)(tv + l * 4);
    __syncthreads();

    // M[y] = dot(slab[y,:], tv) — 32 lanes per row, shuffle reduce
#pragma unroll
    for (int yi = 0; yi < 16; ++yi) {
        const int y = yi * 8 + rg;
        f32x4 a = *(const f32x4*)&slab[y * PITCH + l * 4];
        float p = a[0]*tvv[0] + a[1]*tvv[1] + a[2]*tvv[2] + a[3]*tvv[3];
#pragma unroll
        for (int s = 16; s >= 1; s >>= 1) p += __shfl_xor(p, s, 32);
        if (l == 0) m_s[y] = p;
    }
    __syncthreads();

    // restage op_w into the same slab
#pragma unroll
    for (int i = 0; i < 16; ++i) {
        const int e = i * 1024 + t * 4;
        const int y = e >> 7, z = e & 127;
        *(f32x4*)&slab[y * PITCH + z] = *(const f32x4*)(op_w + e);
    }
    __syncthreads();

    const f32x4 mv = *(const f32x4*)&m_s[l * 4];
#pragma unroll
    for (int ji = 0; ji < 16; ++ji) {
        const int j = ji * 8 + rg;
        f32x4 w = *(const f32x4*)&slab[j * PITCH + l * 4];
        float p = w[0]*mv[0] + w[1]*mv[1] + w[2]*mv[2] + w[3]*mv[3];
#pragma unroll
        for (int s = 16; s >= 1; s >>= 1) p += __shfl_xor(p, s, 32);
        if (l == 0) {
            if (x < D) W2T[j * D + x] = f2bf(p);
            else       bias2[j] = p + op_b[j];
        }
    }
}

// Main: out[b,j] = sum_x we[idx[b],x] * W2[x,j] + bias2[j] via bf16 MFMA.
// 1024 blocks x 128 threads (2 waves). Both waves share the block's 16 rows
// (A-gather L1-shared); wave wv owns column half wv*64. All loads issued
// up-front; 16 MFMAs; 2 waves/SIMD for latency hiding.
__global__ __launch_bounds__(128) void main_mfma(
    const int* __restrict__ idx, const float* __restrict__ we,
    const unsigned short* __restrict__ W2T, const float* __restrict__ bias2,
    float* __restrict__ out)
{
    const int t = threadIdx.x;
    const int wv = t >> 6;            // column half
    const int l = t & 63;
    const int l15 = l & 15, lg = l >> 4;
    const int b0 = blockIdx.x * 16;

    const int g = idx[b0 + l15];
    const float* arow = we + (size_t)g * D;

    // A: 8 x f32x4 (full 128-k row slice for this lane)
    f32x4 a[8];
#pragma unroll
    for (int s = 0; s < 4; ++s) {
        a[2*s]   = *(const f32x4*)(arow + s * 32 + lg * 8);
        a[2*s+1] = *(const f32x4*)(arow + s * 32 + lg * 8 + 4);
    }
    // B: 16 x bh8 from col-major W2T (L2-resident 32 KB)
    bh8 bfr[4][4];
#pragma unroll
    for (int c = 0; c < 4; ++c) {
        const int j = wv * 64 + c * 16 + l15;
#pragma unroll
        for (int s = 0; s < 4; ++s)
            bfr[c][s] = *(const bh8*)(W2T + (size_t)j * D + s * 32 + lg * 8);
    }
    float bias[4];
#pragma unroll
    for (int c = 0; c < 4; ++c) bias[c] = bias2[wv * 64 + c * 16 + l15];

    // convert A to bf16 fragments
    bh8 af[4];
#pragma unroll
    for (int s = 0; s < 4; ++s) {
        af[s][0] = (short)f2bf(a[2*s][0]);   af[s][1] = (short)f2bf(a[2*s][1]);
        af[s][2] = (short)f2bf(a[2*s][2]);   af[s][3] = (short)f2bf(a[2*s][3]);
        af[s][4] = (short)f2bf(a[2*s+1][0]); af[s][5] = (short)f2bf(a[2*s+1][1]);
        af[s][6] = (short)f2bf(a[2*s+1][2]); af[s][7] = (short)f2bf(a[2*s+1][3]);
    }

    f32x4 acc[4];
#pragma unroll
    for (int c = 0; c < 4; ++c) acc[c] = (f32x4){0.f, 0.f, 0.f, 0.f};
#pragma unroll
    for (int s = 0; s < 4; ++s)
#pragma unroll
        for (int c = 0; c < 4; ++c)
            acc[c] = __builtin_amdgcn_mfma_f32_16x16x32_bf16(af[s], bfr[c][s], acc[c], 0, 0, 0);

#pragma unroll
    for (int c = 0; c < 4; ++c)
#pragma unroll
        for (int r = 0; r < 4; ++r)
            out[(size_t)(b0 + lg * 4 + r) * D + wv * 64 + c * 16 + l15] = acc[c][r] + bias[c];
}

extern "C" void kernel_launch(void* const* d_in, const int* in_sizes, int n_in,
                              void* d_out, int out_size, void* d_ws, size_t ws_size,
                              hipStream_t stream) {
    const int*   idx     = (const int*)d_in[0];
    const float* w_embed = (const float*)d_in[1];
    const float* T       = (const float*)d_in[2];
    const float* Bm      = (const float*)d_in[3];
    const float* tv      = (const float*)d_in[4];
    const float* op_w    = (const float*)d_in[5];
    const float* op_b    = (const float*)d_in[6];
    float* out = (float*)d_out;

    unsigned short* W2T = (unsigned short*)d_ws;              // 32768 B
    float* bias2 = (float*)((char*)d_ws + 32768);             // 512 B

    prep<<<D + 1, 256, 0, stream>>>(T, Bm, tv, op_w, op_b, W2T, bias2);
    main_mfma<<<BATCH / 16, 128, 0, stream>>>(idx, w_embed, W2T, bias2, out);
}

// Round 4
// 21.823 us; speedup vs baseline: 1.0910x; 1.0910x over previous
//
#include <hip/hip_runtime.h>

#define D 128
#define BATCH 16384
#define PITCH 132   // slab pitch in floats: 16B-aligned rows, spreads banks

typedef float f32x4 __attribute__((ext_vector_type(4)));
typedef short bh8 __attribute__((ext_vector_type(8)));

__device__ __forceinline__ unsigned short f2bf(float f) {
    unsigned u = __float_as_uint(f);
    u += 0x7FFFu + ((u >> 16) & 1u);   // round-to-nearest-even
    return (unsigned short)(u >> 16);
}

// Fused prep: block x in [0,128]:
//   x < 128: W2T[j][x] = bf16( sum_y (sum_z T[x,y,z] tv[z]) * op_w[j,y] )
//   x ==128: bias2[j]  =       sum_y (sum_z B[y,z]  tv[z]) * op_w[j,y] + op_b[j]
__global__ __launch_bounds__(512) void prep(
    const float* __restrict__ T, const float* __restrict__ Bm,
    const float* __restrict__ tv, const float* __restrict__ op_w,
    const float* __restrict__ op_b, unsigned short* __restrict__ W2T,
    float* __restrict__ bias2)
{
    __shared__ float slab[D * PITCH];
    __shared__ float m_s[D];
    const int x = blockIdx.x;
    const int t = threadIdx.x;    // 0..511
    const int l = t & 31;         // lane within 32-group
    const int rg = t >> 5;        // row group 0..15

    const float* src = (x < D) ? (T + (size_t)x * D * D) : Bm;
    // stage source slab (64 KB) coalesced, 8 f32x4 per thread
#pragma unroll
    for (int i = 0; i < 8; ++i) {
        const int e = i * 2048 + t * 4;
        const int y = e >> 7, z = e & 127;
        *(f32x4*)&slab[y * PITCH + z] = *(const f32x4*)(src + e);
    }
    const f32x4 tvv = *(const f32x4*)(tv + l * 4);
    __syncthreads();

    // M[y] = dot(slab[y,:], tv) — 32 lanes per row, shuffle reduce
#pragma unroll
    for (int yi = 0; yi < 8; ++yi) {
        const int y = yi * 16 + rg;
        f32x4 a = *(const f32x4*)&slab[y * PITCH + l * 4];
        float p = a[0]*tvv[0] + a[1]*tvv[1] + a[2]*tvv[2] + a[3]*tvv[3];
#pragma unroll
        for (int s = 16; s >= 1; s >>= 1) p += __shfl_xor(p, s, 32);
        if (l == 0) m_s[y] = p;
    }
    __syncthreads();

    // restage op_w into the same slab
#pragma unroll
    for (int i = 0; i < 8; ++i) {
        const int e = i * 2048 + t * 4;
        const int y = e >> 7, z = e & 127;
        *(f32x4*)&slab[y * PITCH + z] = *(const f32x4*)(op_w + e);
    }
    __syncthreads();

    const f32x4 mv = *(const f32x4*)&m_s[l * 4];
#pragma unroll
    for (int ji = 0; ji < 8; ++ji) {
        const int j = ji * 16 + rg;
        f32x4 w = *(const f32x4*)&slab[j * PITCH + l * 4];
        float p = w[0]*mv[0] + w[1]*mv[1] + w[2]*mv[2] + w[3]*mv[3];
#pragma unroll
        for (int s = 16; s >= 1; s >>= 1) p += __shfl_xor(p, s, 32);
        if (l == 0) {
            if (x < D) W2T[j * D + x] = f2bf(p);
            else       bias2[j] = p + op_b[j];
        }
    }
}

// Main: out[b,j] = sum_x we[idx[b],x] * W2[x,j] + bias2[j] via bf16 MFMA.
// 1024 blocks x 256 threads (4 waves). All 4 waves share the block's 16 rows
// (A-gather L1-shared); wave wv owns column quarter wv*32 (2 MFMA col-tiles).
// 4096 waves total = 4 waves/SIMD for latency hiding; ~8 MFMAs/wave.
__global__ __launch_bounds__(256) void main_mfma(
    const int* __restrict__ idx, const float* __restrict__ we,
    const unsigned short* __restrict__ W2T, const float* __restrict__ bias2,
    float* __restrict__ out)
{
    const int t = threadIdx.x;
    const int wv = t >> 6;            // column quarter 0..3
    const int l = t & 63;
    const int l15 = l & 15, lg = l >> 4;
    const int b0 = blockIdx.x * 16;

    const int g = idx[b0 + l15];

    // B: 8 x bh8 from col-major W2T (L2/L3-resident 32 KB) — independent, issue first
    bh8 bfr[2][4];
#pragma unroll
    for (int c = 0; c < 2; ++c) {
        const int j = wv * 32 + c * 16 + l15;
#pragma unroll
        for (int s = 0; s < 4; ++s)
            bfr[c][s] = *(const bh8*)(W2T + (size_t)j * D + s * 32 + lg * 8);
    }
    float bias[2];
#pragma unroll
    for (int c = 0; c < 2; ++c) bias[c] = bias2[wv * 32 + c * 16 + l15];

    // A: gather 8 x f32x4 (full 128-k row slice for this lane)
    const float* arow = we + (size_t)g * D;
    f32x4 a[8];
#pragma unroll
    for (int s = 0; s < 4; ++s) {
        a[2*s]   = *(const f32x4*)(arow + s * 32 + lg * 8);
        a[2*s+1] = *(const f32x4*)(arow + s * 32 + lg * 8 + 4);
    }

    // convert A to bf16 fragments
    bh8 af[4];
#pragma unroll
    for (int s = 0; s < 4; ++s) {
        af[s][0] = (short)f2bf(a[2*s][0]);   af[s][1] = (short)f2bf(a[2*s][1]);
        af[s][2] = (short)f2bf(a[2*s][2]);   af[s][3] = (short)f2bf(a[2*s][3]);
        af[s][4] = (short)f2bf(a[2*s+1][0]); af[s][5] = (short)f2bf(a[2*s+1][1]);
        af[s][6] = (short)f2bf(a[2*s+1][2]); af[s][7] = (short)f2bf(a[2*s+1][3]);
    }

    f32x4 acc[2];
#pragma unroll
    for (int c = 0; c < 2; ++c) acc[c] = (f32x4){0.f, 0.f, 0.f, 0.f};
#pragma unroll
    for (int s = 0; s < 4; ++s)
#pragma unroll
        for (int c = 0; c < 2; ++c)
            acc[c] = __builtin_amdgcn_mfma_f32_16x16x32_bf16(af[s], bfr[c][s], acc[c], 0, 0, 0);

#pragma unroll
    for (int c = 0; c < 2; ++c)
#pragma unroll
        for (int r = 0; r < 4; ++r)
            out[(size_t)(b0 + lg * 4 + r) * D + wv * 32 + c * 16 + l15] = acc[c][r] + bias[c];
}

extern "C" void kernel_launch(void* const* d_in, const int* in_sizes, int n_in,
                              void* d_out, int out_size, void* d_ws, size_t ws_size,
                              hipStream_t stream) {
    const int*   idx     = (const int*)d_in[0];
    const float* w_embed = (const float*)d_in[1];
    const float* T       = (const float*)d_in[2];
    const float* Bm      = (const float*)d_in[3];
    const float* tv      = (const float*)d_in[4];
    const float* op_w    = (const float*)d_in[5];
    const float* op_b    = (const float*)d_in[6];
    float* out = (float*)d_out;

    unsigned short* W2T = (unsigned short*)d_ws;              // 32768 B
    float* bias2 = (float*)((char*)d_ws + 32768);             // 512 B

    prep<<<D + 1, 512, 0, stream>>>(T, Bm, tv, op_w, op_b, W2T, bias2);
    main_mfma<<<BATCH / 16, 256, 0, stream>>>(idx, w_embed, W2T, bias2, out);
}